// Round 5
// baseline (1125.022 us; speedup 1.0000x reference)
//
#include <hip/hip_runtime.h>

#define C_N 64
#define I_N 64
#define R_N 36
#define L_N 40
#define D_N 1024
#define S_N 256

#define ATT_LD 40
#define SIMC_LD 264   // 256 data + 8 pad

// ws layout (shorts):
#define OFF_IMG 0
#define OFF_CAP 2359296               // img end
#define OFF_IMT 4980736               // cap end
#define OFF_SLK 8126464               // img_t end (64 zero shorts)
#define OFF_WF  8126528               // W fragment-ordered, 262144 shorts
#define OFF_P   8388672               // p [pair][48*64] bf16, 4096*3072 shorts

typedef float f4 __attribute__((ext_vector_type(4)));
typedef short s16x8 __attribute__((ext_vector_type(8)));

__device__ __forceinline__ unsigned short f2bs(float f) {
    union { float f; unsigned u; } v; v.f = f;
    unsigned r = v.u + 0x7FFFu + ((v.u >> 16) & 1u);
    return (unsigned short)(r >> 16);
}
__device__ __forceinline__ float bs2f(unsigned short s) {
    union { unsigned u; float f; } v; v.u = ((unsigned)s) << 16;
    return v.f;
}

// ---------------- K0: converts ----------------
__global__ void k_convert(const float* __restrict__ img, const float* __restrict__ cap,
                          const float* __restrict__ W, unsigned short* __restrict__ ws) {
    int t = blockIdx.x * 256 + threadIdx.x;
    if (t < I_N * R_N * D_N) ws[OFF_IMG + t] = f2bs(img[t]);
    if (t < C_N * L_N * D_N) ws[OFF_CAP + t] = f2bs(cap[t]);
    if (t < I_N * R_N * D_N) {                 // img_t [i][d][r48]
        int i = t / (R_N * D_N), r = (t / D_N) % R_N, d = t % D_N;
        ws[OFF_IMT + (i * D_N + d) * 48 + r] = f2bs(img[t]);
    }
    if (t < I_N * D_N * 12) {                  // img_t zero rows 36..47
        int i = t / (D_N * 12), d = (t / 12) % D_N, rr = t % 12;
        ws[OFF_IMT + (i * D_N + d) * 48 + 36 + rr] = 0;
    }
    if (t < 64) ws[OFF_SLK + t] = 0;
    if (t < D_N * S_N) {                       // W[d][s] -> fragment-ordered Wfrag
        int d = t >> 8, s = t & 255;
        int nt = s >> 4, ln = s & 15, kc = d >> 5, qq = (d >> 3) & 3, j = d & 7;
        ws[OFF_WF + ((nt * 32 + kc) * 64 + qq * 16 + ln) * 8 + j] = f2bs(W[t]);
    }
}

// ---------------- A: attention probs p, one block per (c,i), 256 thr ----------------
__global__ __launch_bounds__(256, 4)
void k_attn0(const unsigned short* __restrict__ img_b,
             const unsigned short* __restrict__ cap_b,
             unsigned short* __restrict__ pg) {
    __shared__ __align__(16) float s_attn[48 * ATT_LD];

    const int c = blockIdx.x, i = blockIdx.y;
    const int pair = c * I_N + i;
    const int tid = threadIdx.x;
    const int wave = tid >> 6, lane = tid & 63;
    const int q = lane >> 4, ln16 = lane & 15;

    const unsigned short* capc = cap_b + c * (L_N * D_N);
    const unsigned short* imgc = img_b + i * (R_N * D_N);
    unsigned short* pgp = pg + (size_t)pair * 3072;

    // zero-fill pad region of p (rows>=40, cols>=36) — disjoint from live writes below
    for (int k = tid; k < 48 * 64; k += 256) {
        int l = k >> 6, r = k & 63;
        if (l >= L_N || r >= R_N) pgp[k] = 0;
    }
    for (int k = tid; k < 48 * ATT_LD; k += 256) s_attn[k] = 0.f;
    __syncthreads();

    // GEMM1: attn^T[l][r] = cap . img^T, K split over 4 waves (256 each)
    {
        f4 acc[3][3] = {};
        const int kw = wave * 256;
        #pragma unroll
        for (int ks = 0; ks < 8; ++ks) {
            const int kb = kw + ks * 32 + q * 8;
            s16x8 af[3], bfr[3];
            #pragma unroll
            for (int mt = 0; mt < 3; ++mt) {
                int l = mt * 16 + ln16;
                af[mt] = (l < L_N) ? *(const s16x8*)(capc + l * D_N + kb) : (s16x8)0;
            }
            #pragma unroll
            for (int nt = 0; nt < 3; ++nt) {
                int r = nt * 16 + ln16;
                bfr[nt] = (r < R_N) ? *(const s16x8*)(imgc + r * D_N + kb) : (s16x8)0;
            }
            #pragma unroll
            for (int mt = 0; mt < 3; ++mt)
                #pragma unroll
                for (int nt = 0; nt < 3; ++nt)
                    acc[mt][nt] = __builtin_amdgcn_mfma_f32_16x16x32_bf16(af[mt], bfr[nt], acc[mt][nt], 0, 0, 0);
        }
        #pragma unroll
        for (int mt = 0; mt < 3; ++mt)
            #pragma unroll
            for (int nt = 0; nt < 3; ++nt)
                #pragma unroll
                for (int j = 0; j < 4; ++j) {
                    int l = mt * 16 + q * 4 + j;
                    int r = nt * 16 + ln16;
                    if (l < L_N && r < R_N) atomicAdd(&s_attn[l * ATT_LD + r], acc[mt][nt][j]);
                }
    }
    __syncthreads();

    // leaky_relu + l2norm over words (column per region)
    if (tid < R_N) {
        float ss = 0.f;
        #pragma unroll
        for (int l = 0; l < L_N; ++l) {
            float v = s_attn[l * ATT_LD + tid];
            v = (v > 0.f) ? v : 0.1f * v;
            s_attn[l * ATT_LD + tid] = v;
            ss += v * v;
        }
        float inv = 1.f / (sqrtf(ss) + 1e-8f);
        #pragma unroll
        for (int l = 0; l < L_N; ++l) s_attn[l * ATT_LD + tid] *= inv;
    }
    __syncthreads();
    // softmax over regions (row per word) -> p bf16 global
    if (tid < L_N) {
        float mx = -1e30f;
        #pragma unroll
        for (int r = 0; r < R_N; ++r) mx = fmaxf(mx, 9.f * s_attn[tid * ATT_LD + r]);
        float sum = 0.f;
        #pragma unroll
        for (int r = 0; r < R_N; ++r) {
            float e = __expf(9.f * s_attn[tid * ATT_LD + r] - mx);
            s_attn[tid * ATT_LD + r] = e;
            sum += e;
        }
        float inv = 1.f / sum;
        #pragma unroll
        for (int r = 0; r < R_N; ++r)
            pgp[tid * 64 + r] = f2bs(s_attn[tid * ATT_LD + r] * inv);
    }
}

// ---------------- B: GEMM2 + sim + GEMM3 + epilogue, one block per (c,i) ----------------
__global__ __launch_bounds__(512, 4)
void k_main(const unsigned short* __restrict__ pg,
            const unsigned short* __restrict__ cap_b,
            const unsigned short* __restrict__ img_t,
            const unsigned short* __restrict__ wfrag,
            const int* __restrict__ cap_lens,
            const float* __restrict__ bias,
            float* __restrict__ out) {
    __shared__ __align__(16) unsigned short s_sim[48 * SIMC_LD];   // 25344 B
    __shared__ float s_norm[48];
    __shared__ float s_norm2[48];

    const int c = blockIdx.x, i = blockIdx.y;
    const int pair = c * I_N + i;
    const int tid = threadIdx.x;
    const int wave = tid >> 6, lane = tid & 63;
    const int q = lane >> 4, ln16 = lane & 15;

    const unsigned short* capc = cap_b + c * (L_N * D_N);
    const unsigned short* imtc = img_t + (size_t)i * D_N * 48;
    const unsigned short* pgp = pg + (size_t)pair * 3072;

    // init: sim pad rows 40..47 zero; norm accumulators zero
    for (int k = tid; k < 8 * SIMC_LD; k += 512) s_sim[40 * SIMC_LD + k] = 0;
    if (tid < 48) { s_norm[tid] = 0.f; s_norm2[tid] = 0.f; }
    __syncthreads();

    // ---- phase A: GEMM2 norm pass (wave owns 128 d-cols) ----
    {
        float rs[3][4] = {};
        #pragma unroll
        for (int s4 = 0; s4 < 4; ++s4) {
            const int dbase = wave * 128 + s4 * 32;
            f4 a2[3][2] = {};
            #pragma unroll
            for (int ks = 0; ks < 2; ++ks) {
                const int kb = ks * 32 + q * 8;
                s16x8 pf[3];
                #pragma unroll
                for (int mt = 0; mt < 3; ++mt)
                    pf[mt] = *(const s16x8*)(pgp + (mt * 16 + ln16) * 64 + kb);
                #pragma unroll
                for (int nt = 0; nt < 2; ++nt) {
                    const int dcol = dbase + nt * 16 + ln16;
                    s16x8 bfr = *(const s16x8*)(imtc + dcol * 48 + kb);
                    #pragma unroll
                    for (int mt = 0; mt < 3; ++mt)
                        a2[mt][nt] = __builtin_amdgcn_mfma_f32_16x16x32_bf16(pf[mt], bfr, a2[mt][nt], 0, 0, 0);
                }
            }
            #pragma unroll
            for (int mt = 0; mt < 3; ++mt)
                #pragma unroll
                for (int j = 0; j < 4; ++j)
                    rs[mt][j] += a2[mt][0][j] * a2[mt][0][j] + a2[mt][1][j] * a2[mt][1][j];
        }
        #pragma unroll
        for (int mt = 0; mt < 3; ++mt)
            #pragma unroll
            for (int j = 0; j < 4; ++j) {
                float s = rs[mt][j];
                #pragma unroll
                for (int o = 1; o < 16; o <<= 1) s += __shfl_xor(s, o, 64);
                if (ln16 == 0) atomicAdd(&s_norm[mt * 16 + q * 4 + j], s);
            }
    }
    __syncthreads();
    if (tid < 48) s_norm[tid] = 1.f / (sqrtf(s_norm[tid]) + 1e-8f);
    __syncthreads();

    // ---- phase B: per quarter — recompute wc (all 8 waves), sim -> LDS, GEMM3 ----
    f4 acc3[3][2] = {};
    #pragma unroll 1
    for (int Q = 0; Q < 4; ++Q) {
        // GEMM2 recompute: wave owns 32 d-cols of this quarter
        {
            const int dbase = Q * 256 + wave * 32;
            f4 a2[3][2] = {};
            #pragma unroll
            for (int ks = 0; ks < 2; ++ks) {
                const int kb = ks * 32 + q * 8;
                s16x8 pf[3];
                #pragma unroll
                for (int mt = 0; mt < 3; ++mt)
                    pf[mt] = *(const s16x8*)(pgp + (mt * 16 + ln16) * 64 + kb);
                #pragma unroll
                for (int nt = 0; nt < 2; ++nt) {
                    const int dcol = dbase + nt * 16 + ln16;
                    s16x8 bfr = *(const s16x8*)(imtc + dcol * 48 + kb);
                    #pragma unroll
                    for (int mt = 0; mt < 3; ++mt)
                        a2[mt][nt] = __builtin_amdgcn_mfma_f32_16x16x32_bf16(pf[mt], bfr, a2[mt][nt], 0, 0, 0);
                }
            }
            #pragma unroll
            for (int mt = 0; mt < 3; ++mt)
                #pragma unroll
                for (int j = 0; j < 4; ++j) {
                    const int l = mt * 16 + q * 4 + j;
                    if (l < L_N) {
                        const float inv = s_norm[l];
                        #pragma unroll
                        for (int nt = 0; nt < 2; ++nt) {
                            const int cl = wave * 32 + nt * 16 + ln16;   // col within quarter
                            float dv = a2[mt][nt][j] * inv
                                     - bs2f(capc[l * D_N + Q * 256 + cl]);
                            s_sim[l * SIMC_LD + cl] = f2bs(dv * dv);
                        }
                    }
                }
        }
        __syncthreads();
        // GEMM3 partial: wave owns 2 n-tiles; B direct from fragment-ordered global
        #pragma unroll
        for (int kc = 0; kc < 8; ++kc) {
            s16x8 af[3], bf[2];
            #pragma unroll
            for (int mt = 0; mt < 3; ++mt)
                af[mt] = *(const s16x8*)(s_sim + (mt * 16 + ln16) * SIMC_LD + kc * 32 + q * 8);
            #pragma unroll
            for (int u = 0; u < 2; ++u)
                bf[u] = *(const s16x8*)(wfrag + ((size_t)((wave * 2 + u) * 32 + Q * 8 + kc) * 64 + lane) * 8);
            #pragma unroll
            for (int mt = 0; mt < 3; ++mt)
                #pragma unroll
                for (int u = 0; u < 2; ++u)
                    acc3[mt][u] = __builtin_amdgcn_mfma_f32_16x16x32_bf16(af[mt], bf[u], acc3[mt][u], 0, 0, 0);
        }
        __syncthreads();
    }

    // ---- epilogue: +b, relu, l2norm over s, mask, store ----
    const int clen = cap_lens[c];
    float bv[2];
    #pragma unroll
    for (int u = 0; u < 2; ++u) bv[u] = bias[wave * 32 + u * 16 + ln16];
    #pragma unroll
    for (int mt = 0; mt < 3; ++mt)
        #pragma unroll
        for (int j = 0; j < 4; ++j) {
            float s = 0.f;
            #pragma unroll
            for (int u = 0; u < 2; ++u) {
                float v = acc3[mt][u][j] + bv[u];
                v = fmaxf(v, 0.f);
                acc3[mt][u][j] = v;
                s += v * v;
            }
            #pragma unroll
            for (int o = 1; o < 16; o <<= 1) s += __shfl_xor(s, o, 64);
            if (ln16 == 0) atomicAdd(&s_norm2[mt * 16 + q * 4 + j], s);
        }
    __syncthreads();
    if (tid < 48) s_norm2[tid] = 1.f / (sqrtf(s_norm2[tid]) + 1e-8f);
    __syncthreads();
    float* outc = out + (size_t)((c * I_N + i) * L_N) * S_N;
    #pragma unroll
    for (int mt = 0; mt < 3; ++mt)
        #pragma unroll
        for (int j = 0; j < 4; ++j) {
            const int l = mt * 16 + q * 4 + j;
            if (l < L_N) {
                const float sc = (l < clen) ? s_norm2[l] : 0.f;
                #pragma unroll
                for (int u = 0; u < 2; ++u)
                    outc[l * S_N + wave * 32 + u * 16 + ln16] = acc3[mt][u][j] * sc;
            }
        }
}

extern "C" void kernel_launch(void* const* d_in, const int* in_sizes, int n_in,
                              void* d_out, int out_size, void* d_ws, size_t ws_size,
                              hipStream_t stream) {
    const float* img  = (const float*)d_in[0];
    const float* cap  = (const float*)d_in[1];
    const int*   lens = (const int*)d_in[2];
    const float* W    = (const float*)d_in[5];
    const float* bias = (const float*)d_in[6];
    float* out = (float*)d_out;
    unsigned short* ws = (unsigned short*)d_ws;

    k_convert<<<10240, 256, 0, stream>>>(img, cap, W, ws);

    dim3 grid(C_N, I_N);   // c fastest: XCD k gets c%8==k -> cap/Wfrag/img_t L2-resident
    k_attn0<<<grid, 256, 0, stream>>>(ws + OFF_IMG, ws + OFF_CAP, ws + OFF_P);
    k_main<<<grid, 512, 0, stream>>>(ws + OFF_P, ws + OFF_CAP, ws + OFF_IMT, ws + OFF_WF,
                                     lens, bias, out);
}

// Round 6
// 861.303 us; speedup vs baseline: 1.3062x; 1.3062x over previous
//
#include <hip/hip_runtime.h>

#define C_N 64
#define I_N 64
#define R_N 36
#define L_N 40
#define D_N 1024
#define S_N 256

#define P_LD 72   // p row stride (shorts): 144 B, 16B-aligned rows

// ws layout (shorts):
#define OFF_CAP 2359296               // img end
#define OFF_WT  4980736               // cap end
#define OFF_IMT 5242880               // wt end: img_t [i][d][r48]
#define OFF_SLK 8126464               // img_t end: 64 zero shorts (k-overread slack)
#define OFF_SIM 8388672               // sim [pair*40 + l][1024] bf16
#define M_ALL   (C_N * I_N * L_N)

typedef float f4 __attribute__((ext_vector_type(4)));
typedef short s16x8 __attribute__((ext_vector_type(8)));

__device__ __forceinline__ unsigned short f2bs(float f) {
    union { float f; unsigned u; } v; v.f = f;
    unsigned r = v.u + 0x7FFFu + ((v.u >> 16) & 1u);
    return (unsigned short)(r >> 16);
}
__device__ __forceinline__ float bs2f(unsigned short s) {
    union { unsigned u; float f; } v; v.u = ((unsigned)s) << 16;
    return v.f;
}
__device__ __forceinline__ void async16(const unsigned short* g, unsigned short* l) {
    __builtin_amdgcn_global_load_lds(
        (const __attribute__((address_space(1))) unsigned int*)g,
        (__attribute__((address_space(3))) unsigned int*)l, 16, 0, 0);
}

// ---------------- K0: converts ----------------
__global__ void k_convert(const float* __restrict__ img, const float* __restrict__ cap,
                          const float* __restrict__ W, unsigned short* __restrict__ ws) {
    int t = blockIdx.x * 256 + threadIdx.x;
    if (t < I_N * R_N * D_N) ws[t] = f2bs(img[t]);
    if (t < C_N * L_N * D_N) ws[OFF_CAP + t] = f2bs(cap[t]);
    if (t < D_N * S_N) {                       // W[d][s] -> Wt[s][d]
        int d = t >> 8, s = t & 255;
        ws[OFF_WT + s * D_N + d] = f2bs(W[t]);
    }
    if (t < I_N * R_N * D_N) {                 // img_t [i][d][r48]
        int i = t / (R_N * D_N), r = (t / D_N) % R_N, d = t % D_N;
        ws[OFF_IMT + (i * D_N + d) * 48 + r] = f2bs(img[t]);
    }
    if (t < I_N * D_N * 12) {                  // img_t zero rows 36..47
        int i = t / (D_N * 12), d = (t / 12) % D_N, rr = t % 12;
        ws[OFF_IMT + (i * D_N + d) * 48 + 36 + rr] = 0;
    }
    if (t < 64) ws[OFF_SLK + t] = 0;
}

// ---------------- A: one WAVE per (c,i): GEMM1 + softmax (in-register) + GEMM2 + sim.
// Block = 8 waves = c-octet sharing image i. NO __syncthreads anywhere.
__global__ __launch_bounds__(512, 4)
void k_pre(const unsigned short* __restrict__ img_b,
           const unsigned short* __restrict__ cap_b,
           const unsigned short* __restrict__ img_t,
           unsigned short* __restrict__ simg) {
    __shared__ __align__(16) unsigned short s_p[8][48 * P_LD];   // 55296 B

    const int i = blockIdx.y;
    const int wave = threadIdx.x >> 6, lane = threadIdx.x & 63;
    const int c = blockIdx.x * 8 + wave;
    const int pair = c * I_N + i;
    const int q = lane >> 4, ln16 = lane & 15;

    const unsigned short* ai = img_b + i * (R_N * D_N);          // GEMM1 A (m=r)
    const unsigned short* bc = cap_b + c * (L_N * D_N);          // GEMM1 B (n=l), sim cap
    const unsigned short* imtc = img_t + (size_t)i * D_N * 48;   // GEMM2 B (n=d,k=r)
    unsigned short* sp = &s_p[wave][0];

    // zero own p slot (covers m-pad rows 40..47 and k-pad cols 36..71)
    for (int k = lane; k < 48 * P_LD / 2; k += 64) ((unsigned*)sp)[k] = 0;

    // ---- GEMM1: attn[r][l], full K=1024 in this wave ----
    f4 acc[3][3] = {};
    #pragma unroll 4
    for (int ks = 0; ks < 32; ++ks) {
        const int kb = ks * 32 + q * 8;
        s16x8 af[3], bf[3];
        #pragma unroll
        for (int mt = 0; mt < 3; ++mt) {
            int r = mt * 16 + ln16;
            af[mt] = (r < R_N) ? *(const s16x8*)(ai + r * D_N + kb) : (s16x8)0;
        }
        #pragma unroll
        for (int nt = 0; nt < 3; ++nt) {
            int l = nt * 16 + ln16;
            bf[nt] = (l < L_N) ? *(const s16x8*)(bc + l * D_N + kb) : (s16x8)0;
        }
        #pragma unroll
        for (int mt = 0; mt < 3; ++mt)
            #pragma unroll
            for (int nt = 0; nt < 3; ++nt)
                acc[mt][nt] = __builtin_amdgcn_mfma_f32_16x16x32_bf16(af[mt], bf[nt], acc[mt][nt], 0, 0, 0);
    }

    // ---- leaky relu (elementwise) ----
    #pragma unroll
    for (int mt = 0; mt < 3; ++mt)
        #pragma unroll
        for (int nt = 0; nt < 3; ++nt)
            #pragma unroll
            for (int j = 0; j < 4; ++j) {
                float v = acc[mt][nt][j];
                acc[mt][nt][j] = (v > 0.f) ? v : 0.1f * v;
            }
    // ---- l2norm over words l (= nt,ln16 dims) for each region row r ----
    #pragma unroll
    for (int mt = 0; mt < 3; ++mt)
        #pragma unroll
        for (int j = 0; j < 4; ++j) {
            float ss = 0.f;
            #pragma unroll
            for (int nt = 0; nt < 3; ++nt) ss += acc[mt][nt][j] * acc[mt][nt][j];
            #pragma unroll
            for (int o = 1; o < 16; o <<= 1) ss += __shfl_xor(ss, o, 64);
            float inv = 1.f / (sqrtf(ss) + 1e-8f);
            #pragma unroll
            for (int nt = 0; nt < 3; ++nt) acc[mt][nt][j] *= inv;
        }
    // ---- softmax over regions r (= mt,q,j dims) per word l; store p[l][r] to LDS ----
    #pragma unroll
    for (int nt = 0; nt < 3; ++nt) {
        const int l = nt * 16 + ln16;
        float mx = -1e30f;
        #pragma unroll
        for (int mt = 0; mt < 3; ++mt)
            #pragma unroll
            for (int j = 0; j < 4; ++j) {
                int r = mt * 16 + q * 4 + j;
                if (r < R_N) mx = fmaxf(mx, 9.f * acc[mt][nt][j]);
            }
        mx = fmaxf(mx, __shfl_xor(mx, 16, 64));
        mx = fmaxf(mx, __shfl_xor(mx, 32, 64));
        float sum = 0.f;
        #pragma unroll
        for (int mt = 0; mt < 3; ++mt)
            #pragma unroll
            for (int j = 0; j < 4; ++j) {
                int r = mt * 16 + q * 4 + j;
                float e = (r < R_N) ? __expf(9.f * acc[mt][nt][j] - mx) : 0.f;
                acc[mt][nt][j] = e;
                sum += e;
            }
        sum += __shfl_xor(sum, 16, 64);
        sum += __shfl_xor(sum, 32, 64);
        float inv = 1.f / sum;
        #pragma unroll
        for (int mt = 0; mt < 3; ++mt)
            #pragma unroll
            for (int j = 0; j < 4; ++j) {
                int r = mt * 16 + q * 4 + j;
                if (r < R_N && l < L_N) sp[l * P_LD + r] = f2bs(acc[mt][nt][j] * inv);
            }
    }
    // same-wave DS ops complete in order; reads below see the writes (no barrier).

    // ---- GEMM2 A-fragments (p) once: A[m=l][k=r] ----
    s16x8 paf[3][2];
    #pragma unroll
    for (int mt = 0; mt < 3; ++mt)
        #pragma unroll
        for (int ks = 0; ks < 2; ++ks)
            paf[mt][ks] = *(const s16x8*)(sp + (mt * 16 + ln16) * P_LD + ks * 32 + q * 8);

    // ---- GEMM2 pass 1: wc row sumsq (norm over d) — all in registers ----
    float rs[3][4] = {};
    #pragma unroll 2
    for (int ch = 0; ch < 32; ++ch) {
        f4 a2[3][2] = {};
        #pragma unroll
        for (int ks = 0; ks < 2; ++ks) {
            const int kb = ks * 32 + q * 8;
            #pragma unroll
            for (int nt = 0; nt < 2; ++nt) {
                const int dcol = ch * 32 + nt * 16 + ln16;
                s16x8 bfr = *(const s16x8*)(imtc + dcol * 48 + kb);
                #pragma unroll
                for (int mt = 0; mt < 3; ++mt)
                    a2[mt][nt] = __builtin_amdgcn_mfma_f32_16x16x32_bf16(paf[mt][ks], bfr, a2[mt][nt], 0, 0, 0);
            }
        }
        #pragma unroll
        for (int mt = 0; mt < 3; ++mt)
            #pragma unroll
            for (int j = 0; j < 4; ++j)
                rs[mt][j] += a2[mt][0][j] * a2[mt][0][j] + a2[mt][1][j] * a2[mt][1][j];
    }
    float inv2[3][4];
    #pragma unroll
    for (int mt = 0; mt < 3; ++mt)
        #pragma unroll
        for (int j = 0; j < 4; ++j) {
            float s = rs[mt][j];
            #pragma unroll
            for (int o = 1; o < 16; o <<= 1) s += __shfl_xor(s, o, 64);
            inv2[mt][j] = 1.f / (sqrtf(s) + 1e-8f);
        }

    // ---- GEMM2 pass 2: recompute wc, sim=(wc*inv-cap)^2 -> global bf16 ----
    unsigned short* so = simg + (size_t)pair * L_N * D_N;
    #pragma unroll 2
    for (int ch = 0; ch < 32; ++ch) {
        f4 a2[3][2] = {};
        #pragma unroll
        for (int ks = 0; ks < 2; ++ks) {
            const int kb = ks * 32 + q * 8;
            #pragma unroll
            for (int nt = 0; nt < 2; ++nt) {
                const int dcol = ch * 32 + nt * 16 + ln16;
                s16x8 bfr = *(const s16x8*)(imtc + dcol * 48 + kb);
                #pragma unroll
                for (int mt = 0; mt < 3; ++mt)
                    a2[mt][nt] = __builtin_amdgcn_mfma_f32_16x16x32_bf16(paf[mt][ks], bfr, a2[mt][nt], 0, 0, 0);
            }
        }
        #pragma unroll
        for (int mt = 0; mt < 3; ++mt)
            #pragma unroll
            for (int j = 0; j < 4; ++j) {
                const int l = mt * 16 + q * 4 + j;
                if (l < L_N) {
                    #pragma unroll
                    for (int nt = 0; nt < 2; ++nt) {
                        const int dcol = ch * 32 + nt * 16 + ln16;
                        float dv = a2[mt][nt][j] * inv2[mt][j] - bs2f(bc[l * D_N + dcol]);
                        so[l * D_N + dcol] = f2bs(dv * dv);
                    }
                }
            }
    }
}

// ---------------- B: GEMM3  out = l2norm(relu(sim @ W + b)) * mask ----------------
// M=163840, K=1024, N=256. Tile 128x256, BK=64, 8 waves (2 M-groups x 4 N-groups).
__global__ __launch_bounds__(512, 4)
void k_gemm3(const unsigned short* __restrict__ simg,
             const unsigned short* __restrict__ wt,
             const int* __restrict__ cap_lens,
             const float* __restrict__ bias,
             float* __restrict__ out) {
    __shared__ __align__(16) unsigned short sA[128 * 64];   // 16 KB, XOR-swizzled cols
    __shared__ __align__(16) unsigned short sB[256 * 64];   // 32 KB
    __shared__ float s_sum[128];

    const int tid = threadIdx.x;
    const int w = tid >> 6, lane = tid & 63;
    const int ln16 = lane & 15, q = lane >> 4;
    const int wm = (w >> 2) * 64, wn = (w & 3) * 64;
    const int m0 = blockIdx.x * 128;
    const int cgg = ((lane & 7) ^ (lane >> 3)) << 3;   // swizzled source col (shorts)
    const int lrow8 = lane >> 3;
    const int rx = ln16 & 7;

    if (tid < 128) s_sum[tid] = 0.f;

    f4 acc[4][4] = {};
    #pragma unroll 1
    for (int kc = 0; kc < 16; ++kc) {
        const int kofs = kc * 64;
        #pragma unroll
        for (int it = 0; it < 2; ++it) {
            int row = it * 64 + w * 8 + lrow8;
            async16(simg + (size_t)(m0 + row) * D_N + kofs + cgg,
                    sA + (it * 512 + w * 64) * 8);
        }
        #pragma unroll
        for (int it = 0; it < 4; ++it) {
            int row = it * 64 + w * 8 + lrow8;
            async16(wt + (size_t)row * D_N + kofs + cgg,
                    sB + (it * 512 + w * 64) * 8);
        }
        __syncthreads();
        #pragma unroll
        for (int ks = 0; ks < 2; ++ks) {
            const int g = ks * 4 + q;
            s16x8 af[4], bf[4];
            #pragma unroll
            for (int mt = 0; mt < 4; ++mt) {
                int row = wm + mt * 16 + ln16;
                af[mt] = *(const s16x8*)(sA + row * 64 + ((g ^ rx) << 3));
            }
            #pragma unroll
            for (int nt = 0; nt < 4; ++nt) {
                int row = wn + nt * 16 + ln16;
                bf[nt] = *(const s16x8*)(sB + row * 64 + ((g ^ rx) << 3));
            }
            #pragma unroll
            for (int mt = 0; mt < 4; ++mt)
                #pragma unroll
                for (int nt = 0; nt < 4; ++nt)
                    acc[mt][nt] = __builtin_amdgcn_mfma_f32_16x16x32_bf16(af[mt], bf[nt], acc[mt][nt], 0, 0, 0);
        }
        __syncthreads();
    }

    // epilogue: +bias, relu, sumsq over s (cross-wave LDS), l2norm, mask, store
    float bv[4];
    #pragma unroll
    for (int nt = 0; nt < 4; ++nt) bv[nt] = bias[wn + nt * 16 + ln16];
    #pragma unroll
    for (int mt = 0; mt < 4; ++mt)
        #pragma unroll
        for (int j = 0; j < 4; ++j) {
            float s = 0.f;
            #pragma unroll
            for (int nt = 0; nt < 4; ++nt) {
                float v = acc[mt][nt][j] + bv[nt];
                v = fmaxf(v, 0.f);
                acc[mt][nt][j] = v;
                s += v * v;
            }
            #pragma unroll
            for (int o = 1; o < 16; o <<= 1) s += __shfl_xor(s, o, 64);
            if (ln16 == 0) atomicAdd(&s_sum[wm + mt * 16 + q * 4 + j], s);
        }
    __syncthreads();
    if (tid < 128) {
        int grow = m0 + tid;
        int c = grow / (I_N * L_N);
        int l = grow % L_N;
        float inv = 1.f / (sqrtf(s_sum[tid]) + 1e-8f);
        s_sum[tid] = (l < cap_lens[c]) ? inv : 0.f;
    }
    __syncthreads();
    #pragma unroll
    for (int mt = 0; mt < 4; ++mt)
        #pragma unroll
        for (int j = 0; j < 4; ++j) {
            const int rt = wm + mt * 16 + q * 4 + j;
            const float sc = s_sum[rt];
            #pragma unroll
            for (int nt = 0; nt < 4; ++nt)
                out[(size_t)(m0 + rt) * S_N + wn + nt * 16 + ln16] = acc[mt][nt][j] * sc;
        }
}

extern "C" void kernel_launch(void* const* d_in, const int* in_sizes, int n_in,
                              void* d_out, int out_size, void* d_ws, size_t ws_size,
                              hipStream_t stream) {
    const float* img  = (const float*)d_in[0];
    const float* cap  = (const float*)d_in[1];
    const int*   lens = (const int*)d_in[2];
    const float* W    = (const float*)d_in[5];
    const float* bias = (const float*)d_in[6];
    float* out = (float*)d_out;
    unsigned short* ws = (unsigned short*)d_ws;

    k_convert<<<10240, 256, 0, stream>>>(img, cap, W, ws);

    dim3 gridP(8, I_N);   // x = c-octet (-> XCD), y = i; wave w handles c = x*8+w
    k_pre<<<gridP, 512, 0, stream>>>(ws, ws + OFF_CAP, ws + OFF_IMT, ws + OFF_SIM);

    k_gemm3<<<M_ALL / 128, 512, 0, stream>>>(ws + OFF_SIM, ws + OFF_WT, lens, bias, out);
}